// Round 2
// baseline (205.433 us; speedup 1.0000x reference)
//
#include <hip/hip_runtime.h>

// TensorTrain: out[b] = first(x0) . M0(x1) . ... . M29(x30) . last(x31)
// with R=16, D=32, B=262144, selection bits in {0,1}.
//
// Strategy: meet-in-the-middle table precompute, built in ONE kernel.
//   prefix p = bits x0..x15  (x0 = MSB)  -> V16[p] : R row-vector
//   suffix s = bits x16..x31 (x16 = MSB) -> W16[s] : R col-vector
//   out = V16[p] . W16[s]
// tt_build: 512 blocks x 256 threads. Block h<256 computes V16 rows
// [h*256, h*256+256); block h>=256 the same slice of W16.
//
// Round-1 lesson (rocprof): chain math read cores_mid straight from global
// with per-thread scalar stride-2 loads -> latency-bound, VALUBusy 7%,
// 120+ us. Fix: stage the 15 needed cores into LDS ONCE per block with
// coalesced float2 loads, de-interleaving the selection bit so the layout
// is [core][bit][r*16+s]. Every matvec row read is then 64 B contiguous
// LDS (broadcast ds_read_b128, <=2 distinct addrs per wave -> conflict
// free) instead of ~200-cycle scattered global hits.

#define R 16
#define TT_D 32
#define BATCH 262144

// workspace layout, in floats (only the final 16-bit tables)
#define OFF_V16  0                      // 65536 x 16
#define OFF_W16  1048576                // 65536 x 16
#define WS_FLOATS 2097152               // 8 MB

// LDS padding for the nibble product tables: stride 268 floats
// (268 % 32 = 12 -> the 4 distinct rows a wave touches in phase 3 land on
// distinct banks; natural 256 stride is a 4-way conflict). 268*4 = 1072 B,
// 16 B aligned so b128 ops still apply.
#define MSTRIDE 268
#define VSTRIDE 17

// Row r of the product of 4 staged cores scm[lbase..lbase+3] selected by the
// 4 bits of e (MSB first). scm layout: [core][bit][r*16+s] (512 floats/core).
__device__ __forceinline__ void row_chain4_lds(const float* __restrict__ scm, int lbase,
                                               int e, int r, float* __restrict__ out) {
    const int b0 = (e >> 3) & 1, b1 = (e >> 2) & 1, b2 = (e >> 1) & 1, b3 = e & 1;
    float v[R], nv[R];
    const float* M0 = scm + lbase * 512 + b0 * 256;
    #pragma unroll
    for (int s = 0; s < R; s++) v[s] = M0[r * 16 + s];
    const int bits[3] = { b1, b2, b3 };
    #pragma unroll
    for (int k = 1; k <= 3; k++) {
        const float* M = scm + (lbase + k) * 512 + bits[k - 1] * 256;
        #pragma unroll
        for (int s = 0; s < R; s++) nv[s] = 0.f;
        #pragma unroll
        for (int t2 = 0; t2 < R; t2++) {
            const float a = v[t2];
            #pragma unroll
            for (int s = 0; s < R; s++) nv[s] += a * M[t2 * 16 + s];   // 64B row read
        }
        #pragma unroll
        for (int s = 0; s < R; s++) v[s] = nv[s];
    }
    #pragma unroll
    for (int s = 0; s < R; s++) out[s] = v[s];
}

// ---------------------------------------------------------------------------
// Fused table build. Blocks 0..255: V16 slice h; blocks 256..511: W16 slice.
__global__ __launch_bounds__(256) void tt_build(const float* __restrict__ cf,
                                                const float* __restrict__ cm,
                                                const float* __restrict__ cl,
                                                float* __restrict__ ws) {
    __shared__ float scm[15 * 512];     // staged cores, bit-deinterleaved (30 KB)
    __shared__ float T0[16 * MSTRIDE];  // prefix: B (M7..M10) ; suffix: F (M23..M26)
    __shared__ float T1[16 * MSTRIDE];  // prefix: C (M11..M14); suffix: W4 vecs (stride 17)
    __shared__ float SA[16 * VSTRIDE];  // prefix: A[h&15] rows; suffix: Dm[h>>4] rows
    __shared__ float SE[16 * VSTRIDE];  // suffix: E[h&15] rows
    __shared__ float SV[32];            // prefix: [0:16) V4[h>>4], [16:32) v8 = V4@A
    __shared__ float SG[256];           // suffix: G = Dm @ E

    const int t = threadIdx.x;
    const int e = t >> 4, r = t & 15;
    const bool isPrefix = (blockIdx.x < 256);
    float tmp[R];

    // ---- phase 0: stage this half's 15 cores into LDS, de-interleaved ----
    {
        const int cbase = isPrefix ? 0 : 15;
        const float2* cm2 = (const float2*)(cm + cbase * 512);
        #pragma unroll
        for (int j = t; j < 15 * 256; j += 256) {
            const float2 vv = cm2[j];                 // coalesced 8B loads
            const int ci = j >> 8, idx = j & 255;
            scm[ci * 512 + idx] = vv.x;               // bit 0 plane
            scm[ci * 512 + 256 + idx] = vv.y;         // bit 1 plane
        }
    }
    __syncthreads();

    if (isPrefix) {
        const int h = blockIdx.x;
        // ---- phase 1: nibble tables into LDS (all math from scm) ----
        row_chain4_lds(scm, 7, e, r, tmp);               // B rows (x8..x11)
        #pragma unroll
        for (int s = 0; s < R; s++) T0[e * MSTRIDE + r * 16 + s] = tmp[s];
        row_chain4_lds(scm, 11, e, r, tmp);              // C rows (x12..x15)
        #pragma unroll
        for (int s = 0; s < R; s++) T1[e * MSTRIDE + r * 16 + s] = tmp[s];
        if (t < 16) {                                    // A[h&15] row t (x4..x7)
            row_chain4_lds(scm, 3, h & 15, t, tmp);
            #pragma unroll
            for (int s = 0; s < R; s++) SA[t * VSTRIDE + s] = tmp[s];
        } else if (t == 16) {                            // V4[h>>4] = first@M0@M1@M2
            const int n0 = h >> 4;
            const int b0 = (n0 >> 3) & 1, b1 = (n0 >> 2) & 1, b2 = (n0 >> 1) & 1, b3 = n0 & 1;
            float v[R], nv[R];
            #pragma unroll
            for (int s = 0; s < R; s++) v[s] = cf[s * 2 + b0];
            const int bits[3] = { b1, b2, b3 };
            #pragma unroll
            for (int k = 0; k < 3; k++) {
                const float* M = scm + k * 512 + bits[k] * 256;
                #pragma unroll
                for (int s = 0; s < R; s++) nv[s] = 0.f;
                #pragma unroll
                for (int t2 = 0; t2 < R; t2++) {
                    const float a = v[t2];
                    #pragma unroll
                    for (int s = 0; s < R; s++) nv[s] += a * M[t2 * 16 + s];
                }
                #pragma unroll
                for (int s = 0; s < R; s++) v[s] = nv[s];
            }
            #pragma unroll
            for (int s = 0; s < R; s++) SV[s] = v[s];
        }
        __syncthreads();
        // ---- phase 2: v8 = V4[h>>4] @ A[h&15] (one element per thread) ----
        if (t < 16) {
            float a = 0.f;
            #pragma unroll
            for (int k = 0; k < R; k++) a += SV[k] * SA[k * VSTRIDE + t];
            SV[16 + t] = a;
        }
        __syncthreads();
        // ---- phase 3: V16[h*256+t] = ((v8 @ B[t>>4]) @ C[t&15]) ----
        const float* Bm = T0 + (t >> 4) * MSTRIDE;
        const float* Cm = T1 + (t & 15) * MSTRIDE;
        float u1[R];
        #pragma unroll
        for (int s = 0; s < R; s++) u1[s] = 0.f;
        #pragma unroll
        for (int k = 0; k < R; k++) {
            const float a = SV[16 + k];
            #pragma unroll
            for (int s = 0; s < R; s++) u1[s] += a * Bm[k * 16 + s];
        }
        float u2[R];
        #pragma unroll
        for (int s = 0; s < R; s++) u2[s] = 0.f;
        #pragma unroll
        for (int k = 0; k < R; k++) {
            const float a = u1[k];
            #pragma unroll
            for (int s = 0; s < R; s++) u2[s] += a * Cm[k * 16 + s];
        }
        float* o = ws + OFF_V16 + (size_t)((int)blockIdx.x * 256 + t) * 16;
        #pragma unroll
        for (int s = 0; s < R; s++) o[s] = u2[s];
    } else {
        const int h = blockIdx.x - 256;
        // local core index = global - 15: Dm=0, E=4, F=8, W4 cores 27..29 -> 12..14
        // ---- phase 1: nibble tables into LDS ----
        row_chain4_lds(scm, 8, e, r, tmp);               // F rows (x24..x27)
        #pragma unroll
        for (int s = 0; s < R; s++) T0[e * MSTRIDE + r * 16 + s] = tmp[s];
        if (t < 16) {                                    // W4[t] = M27@M28@M29@last
            const int b0 = (t >> 3) & 1, b1 = (t >> 2) & 1, b2 = (t >> 1) & 1, b3 = t & 1;
            float w[R], nw[R];
            #pragma unroll
            for (int r2 = 0; r2 < R; r2++) w[r2] = cl[r2 * 2 + b3];
            const int lcores[3] = { 14, 13, 12 };        // M29, M28, M27
            const int bits[3] = { b2, b1, b0 };
            #pragma unroll
            for (int k = 0; k < 3; k++) {
                const float* M = scm + lcores[k] * 512 + bits[k] * 256;
                #pragma unroll
                for (int r2 = 0; r2 < R; r2++) {
                    float a = 0.f;
                    #pragma unroll
                    for (int t2 = 0; t2 < R; t2++) a += M[r2 * 16 + t2] * w[t2];
                    nw[r2] = a;
                }
                #pragma unroll
                for (int r2 = 0; r2 < R; r2++) w[r2] = nw[r2];
            }
            #pragma unroll
            for (int r2 = 0; r2 < R; r2++) T1[t * VSTRIDE + r2] = w[r2];
        } else if (t >= 64 && t < 80) {                  // Dm[h>>4] row (x16..x19)
            row_chain4_lds(scm, 0, h >> 4, t - 64, tmp);
            #pragma unroll
            for (int s = 0; s < R; s++) SA[(t - 64) * VSTRIDE + s] = tmp[s];
        } else if (t >= 80 && t < 96) {                  // E[h&15] row (x20..x23)
            row_chain4_lds(scm, 4, h & 15, t - 80, tmp);
            #pragma unroll
            for (int s = 0; s < R; s++) SE[(t - 80) * VSTRIDE + s] = tmp[s];
        }
        __syncthreads();
        // ---- phase 2: G = Dm[h>>4] @ E[h&15] (one element per thread) ----
        {
            const int gr = t >> 4, gc = t & 15;
            float a = 0.f;
            #pragma unroll
            for (int k = 0; k < R; k++) a += SA[gr * VSTRIDE + k] * SE[k * VSTRIDE + gc];
            SG[t] = a;
        }
        __syncthreads();
        // ---- phase 3: W16[h*256+t] = G @ (F[t>>4] @ W4[t&15]) ----
        const float* Fm = T0 + (t >> 4) * MSTRIDE;
        const float* w4 = T1 + (t & 15) * VSTRIDE;
        float w[R];
        #pragma unroll
        for (int r2 = 0; r2 < R; r2++) {
            float a = 0.f;
            #pragma unroll
            for (int k = 0; k < R; k++) a += Fm[r2 * 16 + k] * w4[k];
            w[r2] = a;
        }
        float o2[R];
        #pragma unroll
        for (int r2 = 0; r2 < R; r2++) {
            float a = 0.f;
            #pragma unroll
            for (int c = 0; c < R; c++) a += SG[r2 * 16 + c] * w[c];
            o2[r2] = a;
        }
        float* o = ws + OFF_W16 + (size_t)(h * 256 + t) * 16;
        #pragma unroll
        for (int r2 = 0; r2 < R; r2++) o[r2] = o2[r2];
    }
}

// ---------------------------------------------------------------------------
// Kernel D: main. One thread per batch element: read 32 bits, two 64 B
// gathers, 16-wide dot.
__global__ __launch_bounds__(256) void tt_main(const int* __restrict__ X,
                                               const float* __restrict__ ws,
                                               float* __restrict__ out) {
    const int b = blockIdx.x * 256 + threadIdx.x;
    const int4* Xr = (const int4*)(X + (size_t)b * TT_D);
    int xv[TT_D];
    #pragma unroll
    for (int q = 0; q < 8; q++) {
        int4 c = Xr[q];
        xv[q * 4 + 0] = c.x; xv[q * 4 + 1] = c.y; xv[q * 4 + 2] = c.z; xv[q * 4 + 3] = c.w;
    }
    unsigned p = 0, s = 0;
    #pragma unroll
    for (int i = 0; i < 16; i++) p = (p << 1) | (unsigned)(xv[i] & 1);
    #pragma unroll
    for (int i = 16; i < 32; i++) s = (s << 1) | (unsigned)(xv[i] & 1);

    const float4* v = (const float4*)(ws + OFF_V16 + (size_t)p * 16);
    const float4* w = (const float4*)(ws + OFF_W16 + (size_t)s * 16);
    float acc = 0.f;
    #pragma unroll
    for (int k = 0; k < 4; k++) {
        float4 a = v[k], c = w[k];
        acc += a.x * c.x + a.y * c.y + a.z * c.z + a.w * c.w;
    }
    out[b] = acc;
}

// ---------------------------------------------------------------------------
// Fallback: direct per-thread chain (used only if ws too small). Correct but
// slow (~LDS-bound).
__global__ __launch_bounds__(256) void tt_direct(const int* __restrict__ X,
                                                 const float* __restrict__ cf,
                                                 const float* __restrict__ cm,
                                                 const float* __restrict__ cl,
                                                 float* __restrict__ out) {
    __shared__ float scm[30 * 16 * 16 * 2];
    for (int i = threadIdx.x; i < 30 * 16 * 16 * 2; i += blockDim.x) scm[i] = cm[i];
    __syncthreads();
    const int b = blockIdx.x * blockDim.x + threadIdx.x;
    if (b >= BATCH) return;
    const int* xr = X + (size_t)b * TT_D;
    float v[R], nv[R];
    const int x0 = xr[0] & 1;
    #pragma unroll
    for (int r = 0; r < R; r++) v[r] = cf[r * 2 + x0];
    for (int i = 1; i <= 30; i++) {
        const int bit = xr[i] & 1;
        const float* M = scm + (i - 1) * 512;
        #pragma unroll
        for (int s2 = 0; s2 < R; s2++) {
            float acc = 0.f;
            #pragma unroll
            for (int r = 0; r < R; r++) acc += v[r] * M[(r * 16 + s2) * 2 + bit];
            nv[s2] = acc;
        }
        #pragma unroll
        for (int s2 = 0; s2 < R; s2++) v[s2] = nv[s2];
    }
    const int xl = xr[31] & 1;
    float acc = 0.f;
    #pragma unroll
    for (int r = 0; r < R; r++) acc += v[r] * cl[r * 2 + xl];
    out[b] = acc;
}

extern "C" void kernel_launch(void* const* d_in, const int* in_sizes, int n_in,
                              void* d_out, int out_size, void* d_ws, size_t ws_size,
                              hipStream_t stream) {
    const int* X = (const int*)d_in[0];
    const float* cf = (const float*)d_in[1];
    const float* cm = (const float*)d_in[2];
    const float* cl = (const float*)d_in[3];
    float* out = (float*)d_out;

    if (ws_size >= (size_t)WS_FLOATS * sizeof(float)) {
        float* ws = (float*)d_ws;
        tt_build<<<512, 256, 0, stream>>>(cf, cm, cl, ws);
        tt_main<<<BATCH / 256, 256, 0, stream>>>(X, ws, out);
    } else {
        tt_direct<<<(BATCH + 255) / 256, 256, 0, stream>>>(X, cf, cm, cl, out);
    }
}

// Round 3
// 111.389 us; speedup vs baseline: 1.8443x; 1.8443x over previous
//
#include <hip/hip_runtime.h>

// TensorTrain: out[b] = first(x0) . M0(x1) . ... . M29(x30) . last(x31)
// with R=16, D=32, B=262144, selection bits in {0,1}.
//
// Meet-in-the-middle: V16[p] (prefix row-vec) . W16[s] (suffix col-vec).
// tt_build: 512 blocks x 256 threads, block h<256 -> V16 slice, else W16.
//
// Round-2 lesson (rocprof): both the global-read and LDS-staged variants sat
// at ~140 us with VALUBusy 7%, HBM 1%, no conflicts -> neither data-memory
// nor VALU bound. The shared trait: ~90 KB of fully-unrolled straight-line
// code per path -> instruction-fetch streaming from L2 with no I-cache reuse.
// This version keeps the exact same math but with ROLLED outer loops around
// one fully-unrolled 16x16 matvec body (inner unroll is required so register
// arrays stay statically indexed), runtime pointer selection instead of
// duplicated call sites. ~5x smaller code.

#define R 16
#define TT_D 32
#define BATCH 262144

// workspace layout, in floats (only the final 16-bit tables)
#define OFF_V16  0                      // 65536 x 16
#define OFF_W16  1048576                // 65536 x 16
#define WS_FLOATS 2097152               // 8 MB

// LDS padding: nibble-table stride 268 floats (268 % 32 = 12 -> the 4
// distinct rows a wave touches land on distinct banks; 256 would be 4-way).
#define MSTRIDE 268
#define VSTRIDE 17

// u (registers, row-vec) = u @ M, M row-major 16x16 in LDS.
// Inner fully unrolled: static indexing keeps u/nv in VGPRs (rule #20).
__device__ __forceinline__ void rowvec_mat(const float* __restrict__ M,
                                           float* __restrict__ u) {
    float nv[R];
    #pragma unroll
    for (int s = 0; s < R; s++) nv[s] = 0.f;
    #pragma unroll
    for (int t2 = 0; t2 < R; t2++) {
        const float a = u[t2];
        #pragma unroll
        for (int s = 0; s < R; s++) nv[s] += a * M[t2 * 16 + s];
    }
    #pragma unroll
    for (int s = 0; s < R; s++) u[s] = nv[s];
}

// w (registers, col-vec) = M @ w.
__device__ __forceinline__ void mat_colvec(const float* __restrict__ M,
                                           float* __restrict__ w) {
    float nw[R];
    #pragma unroll
    for (int r2 = 0; r2 < R; r2++) {
        float a = 0.f;
        #pragma unroll
        for (int k = 0; k < R; k++) a += M[r2 * 16 + k] * w[k];
        nw[r2] = a;
    }
    #pragma unroll
    for (int r2 = 0; r2 < R; r2++) w[r2] = nw[r2];
}

// Row r of M[lbase](b0) @ M[lbase+1](b1) @ M[lbase+2](b2) @ M[lbase+3](b3),
// bits of e MSB-first. scm layout: [core][bit][r*16+s], 512 floats/core.
// k-loop rolled: one rowvec_mat copy per call site.
__device__ __forceinline__ void chain4_row(const float* __restrict__ scm, int lbase,
                                           int e, int r, float* __restrict__ u) {
    const float* M0 = scm + lbase * 512 + ((e >> 3) & 1) * 256;
    #pragma unroll
    for (int s = 0; s < R; s++) u[s] = M0[r * 16 + s];
    for (int k = 1; k <= 3; k++) {
        const float* M = scm + (lbase + k) * 512 + ((e >> (3 - k)) & 1) * 256;
        rowvec_mat(M, u);
    }
}

// ---------------------------------------------------------------------------
__global__ __launch_bounds__(256) void tt_build(const float* __restrict__ cf,
                                                const float* __restrict__ cm,
                                                const float* __restrict__ cl,
                                                float* __restrict__ ws) {
    __shared__ float scm[15 * 512];     // staged cores, bit-deinterleaved (30 KB)
    __shared__ float T0[16 * MSTRIDE];  // prefix: B=M7..10 ; suffix: F=M23..26
    __shared__ float T1[16 * MSTRIDE];  // prefix: C=M11..14; suffix: W4 vecs (VSTRIDE)
    __shared__ float SA[16 * VSTRIDE];  // suffix: Dm[h>>4] rows
    __shared__ float SE[16 * VSTRIDE];  // suffix: E[h&15] rows
    __shared__ float SV[16];            // prefix: v8 = first@M0..M6
    __shared__ float SG[256];           // suffix: G = Dm @ E

    const int t = threadIdx.x;
    const int e = t >> 4, r = t & 15;
    const bool isPrefix = (blockIdx.x < 256);
    const int h = isPrefix ? blockIdx.x : (blockIdx.x - 256);

    // ---- phase 0: stage this half's 15 cores into LDS, bit-deinterleaved ----
    {
        const float2* cm2 = (const float2*)(cm + (isPrefix ? 0 : 15) * 512);
        for (int j = t; j < 15 * 256; j += 256) {
            const float2 vv = cm2[j];                 // coalesced 8B loads
            const int ci = j >> 8, idx = j & 255;
            scm[ci * 512 + idx] = vv.x;               // bit 0 plane
            scm[ci * 512 + 256 + idx] = vv.y;         // bit 1 plane
        }
    }
    __syncthreads();

    if (isPrefix) {
        // ---- phase 1a: wave0 lanes 0-15, column-parallel v8 chain ----
        // v8 = first(x0).M0(x1)...M6(x7), x0 = h>>7, M_j bit = (h>>(6-j))&1.
        if (t < 16) {
            SV[t] = cf[t * 2 + ((h >> 7) & 1)];
            for (int j = 0; j < 7; j++) {
                const float* M = scm + j * 512 + (((h >> (6 - j)) & 1) << 8);
                float a = 0.f;
                #pragma unroll
                for (int t2 = 0; t2 < R; t2++) a += SV[t2] * M[t2 * 16 + t];
                SV[t] = a;   // single wave: all lane reads precede this write
            }
        }
        // ---- phase 1b: nibble tables B (x8..11) -> T0, C (x12..15) -> T1 ----
        {
            float u[R];
            for (int tab = 0; tab < 2; tab++) {
                chain4_row(scm, 7 + 4 * tab, e, r, u);
                float* dst = (tab ? T1 : T0) + e * MSTRIDE + r * 16;
                #pragma unroll
                for (int s = 0; s < R; s++) dst[s] = u[s];
            }
        }
        __syncthreads();
        // ---- phase 2: V16[h*256+t] = v8 @ B[t>>4] @ C[t&15] ----
        float v[R];
        #pragma unroll
        for (int k = 0; k < R; k++) v[k] = SV[k];     // broadcast
        const float* src = T0 + (t >> 4) * MSTRIDE;
        for (int q = 0; q < 2; q++) {
            rowvec_mat(src, v);
            src = T1 + (t & 15) * MSTRIDE;
        }
        float* o = ws + OFF_V16 + (size_t)(h * 256 + t) * 16;
        #pragma unroll
        for (int s = 0; s < R; s++) o[s] = v[s];
    } else {
        // local core index = global - 15: Dm(M15..18)=0, E(M19..22)=4,
        // F(M23..26)=8, M27..29 -> 12..14.
        // ---- phase 1: F rows by all threads; Dm/E rows by t in [16,48);
        //               W4 vectors by t in [48,64) ----
        {
            float u[R];
            for (int job = 0; job < 2; job++) {
                int lb, ee, rr;
                float* dst;
                bool active = true;
                if (job == 0)      { lb = 8; ee = e;      rr = r;      dst = T0 + e * MSTRIDE + r * 16; }
                else if (t < 16)   { lb = 0; ee = h >> 4; rr = t;      dst = SA + t * VSTRIDE; }
                else if (t < 32)   { lb = 4; ee = h & 15; rr = t - 16; dst = SE + (t - 16) * VSTRIDE; }
                else               { active = false; lb = 0; ee = 0; rr = 0; dst = nullptr; }
                if (active) {
                    chain4_row(scm, lb, ee, rr, u);
                    #pragma unroll
                    for (int s = 0; s < R; s++) dst[s] = u[s];
                }
            }
        }
        if (t >= 48 && t < 64) {                      // W4[l] = M27(l3)M28(l2)M29(l1).last(l0)
            const int l = t - 48;
            float w[R];
            #pragma unroll
            for (int r2 = 0; r2 < R; r2++) w[r2] = cl[r2 * 2 + (l & 1)];
            for (int k = 0; k < 3; k++) {             // M29, M28, M27
                const float* M = scm + (14 - k) * 512 + (((l >> (k + 1)) & 1) << 8);
                mat_colvec(M, w);
            }
            float* dst = T1 + l * VSTRIDE;
            #pragma unroll
            for (int r2 = 0; r2 < R; r2++) dst[r2] = w[r2];
        }
        __syncthreads();
        // ---- phase 2: G = Dm[h>>4] @ E[h&15] (one element per thread) ----
        {
            const int gr = t >> 4, gc = t & 15;
            float a = 0.f;
            #pragma unroll
            for (int k = 0; k < R; k++) a += SA[gr * VSTRIDE + k] * SE[k * VSTRIDE + gc];
            SG[gr * 16 + gc] = a;
        }
        __syncthreads();
        // ---- phase 3: W16[h*256+t] = G @ (F[t>>4] @ W4[t&15]) ----
        float w[R];
        #pragma unroll
        for (int k = 0; k < R; k++) w[k] = T1[(t & 15) * VSTRIDE + k];
        const float* src = T0 + (t >> 4) * MSTRIDE;
        for (int q = 0; q < 2; q++) {
            mat_colvec(src, w);
            src = SG;
        }
        float* o = ws + OFF_W16 + (size_t)(h * 256 + t) * 16;
        #pragma unroll
        for (int r2 = 0; r2 < R; r2++) o[r2] = w[r2];
    }
}

// ---------------------------------------------------------------------------
// Main: one thread per batch element: 128B X read, two 64B table gathers,
// 16-wide dot.
__global__ __launch_bounds__(256) void tt_main(const int* __restrict__ X,
                                               const float* __restrict__ ws,
                                               float* __restrict__ out) {
    const int b = blockIdx.x * 256 + threadIdx.x;
    const int4* Xr = (const int4*)(X + (size_t)b * TT_D);
    int xv[TT_D];
    #pragma unroll
    for (int q = 0; q < 8; q++) {
        int4 c = Xr[q];
        xv[q * 4 + 0] = c.x; xv[q * 4 + 1] = c.y; xv[q * 4 + 2] = c.z; xv[q * 4 + 3] = c.w;
    }
    unsigned p = 0, s = 0;
    #pragma unroll
    for (int i = 0; i < 16; i++) p = (p << 1) | (unsigned)(xv[i] & 1);
    #pragma unroll
    for (int i = 16; i < 32; i++) s = (s << 1) | (unsigned)(xv[i] & 1);

    const float4* v = (const float4*)(ws + OFF_V16 + (size_t)p * 16);
    const float4* w = (const float4*)(ws + OFF_W16 + (size_t)s * 16);
    float acc = 0.f;
    #pragma unroll
    for (int k = 0; k < 4; k++) {
        float4 a = v[k], c = w[k];
        acc += a.x * c.x + a.y * c.y + a.z * c.z + a.w * c.w;
    }
    out[b] = acc;
}

// ---------------------------------------------------------------------------
// Fallback: direct per-thread chain (used only if ws too small).
__global__ __launch_bounds__(256) void tt_direct(const int* __restrict__ X,
                                                 const float* __restrict__ cf,
                                                 const float* __restrict__ cm,
                                                 const float* __restrict__ cl,
                                                 float* __restrict__ out) {
    __shared__ float scm[30 * 16 * 16 * 2];
    for (int i = threadIdx.x; i < 30 * 16 * 16 * 2; i += blockDim.x) scm[i] = cm[i];
    __syncthreads();
    const int b = blockIdx.x * blockDim.x + threadIdx.x;
    if (b >= BATCH) return;
    const int* xr = X + (size_t)b * TT_D;
    float v[R], nv[R];
    const int x0 = xr[0] & 1;
    #pragma unroll
    for (int rr = 0; rr < R; rr++) v[rr] = cf[rr * 2 + x0];
    for (int i = 1; i <= 30; i++) {
        const int bit = xr[i] & 1;
        const float* M = scm + (i - 1) * 512;
        #pragma unroll
        for (int s2 = 0; s2 < R; s2++) {
            float acc = 0.f;
            #pragma unroll
            for (int rr = 0; rr < R; rr++) acc += v[rr] * M[(rr * 16 + s2) * 2 + bit];
            nv[s2] = acc;
        }
        #pragma unroll
        for (int s2 = 0; s2 < R; s2++) v[s2] = nv[s2];
    }
    const int xl = xr[31] & 1;
    float acc = 0.f;
    #pragma unroll
    for (int rr = 0; rr < R; rr++) acc += v[rr] * cl[rr * 2 + xl];
    out[b] = acc;
}

extern "C" void kernel_launch(void* const* d_in, const int* in_sizes, int n_in,
                              void* d_out, int out_size, void* d_ws, size_t ws_size,
                              hipStream_t stream) {
    const int* X = (const int*)d_in[0];
    const float* cf = (const float*)d_in[1];
    const float* cm = (const float*)d_in[2];
    const float* cl = (const float*)d_in[3];
    float* out = (float*)d_out;

    if (ws_size >= (size_t)WS_FLOATS * sizeof(float)) {
        float* ws = (float*)d_ws;
        tt_build<<<512, 256, 0, stream>>>(cf, cm, cl, ws);
        tt_main<<<BATCH / 256, 256, 0, stream>>>(X, ws, out);
    } else {
        tt_direct<<<(BATCH + 255) / 256, 256, 0, stream>>>(X, cf, cm, cl, out);
    }
}